// Round 19
// baseline (147.056 us; speedup 1.0000x reference)
//
#include <hip/hip_runtime.h>
#include <hip/hip_bf16.h>
#include <cstdint>

#define NHEADS 8
#define NPOINTS 4

typedef __bf16 bf16x8 __attribute__((ext_vector_type(8)));
typedef float f32x4 __attribute__((ext_vector_type(4)));

#define AS1 __attribute__((address_space(1)))
#define AS3 __attribute__((address_space(3)))

__device__ __forceinline__ ushort f2bf_rn(float x) {
  union { float f; uint32_t u; } c; c.f = x;
  uint32_t r = c.u + 0x7fffu + ((c.u >> 16) & 1u);
  return (ushort)(r >> 16);
}
__device__ __forceinline__ float bf2f(ushort h) {
  union { uint32_t u; float f; } c; c.u = ((uint32_t)h) << 16; return c.f;
}
__device__ __forceinline__ uint pack2(ushort a, ushort b) {
  return (uint)a | ((uint)b << 16);
}

// 64-B-row layout (r15, verified): 4 granules of 16 B, pos = seg ^ fr(row).
__device__ __forceinline__ int fr(int row) { return (row >> 1) & 3; }
__device__ __forceinline__ int aidx(int row, int gpos) { return row * 32 + gpos * 8; }

// 128-B-row split layout (r5-r13, verified): 8 granules, 0-3 hi / 4-7 lo,
// granule pos XOR-swizzled by (row&7).
__device__ __forceinline__ int gidx8(int row, int g0) {
  return row * 64 + ((g0 ^ (row & 7)) << 3);
}

// ---------------------------------------------------------------------------
// Pure-bf16 GEMM, N=256 (r15 structure + r19 2-deep A prefetch):
// B hi-only bf16, A+B LDS double-buffered, B(t+1) glds a full step before
// the draining sync. A register prefetch now 2 STEPS deep (two named reg
// sets, unroll-by-2): A(t+2) issued at step t, consumed at step t+1's end
// -> ~800cy load->use distance vs HBM ~900cy (was ~400).
// ABF16: A arrives bf16 (gemm2's mid) -> A-stage is a pure uint2 copy.
// LDS = 2*(TM*64B) + 2*16KB = 40 KB @ TM=64 -> 4 blocks/CU.
// ---------------------------------------------------------------------------
template<int TM, bool CBF16, bool ABF16>
__global__ __launch_bounds__(256, 4) void gemm_bf16_n256(
    const void* __restrict__ Ain,
    const ushort* __restrict__ Bprep,   // [K/32][8192] pre-swizzled ushorts
    const float* __restrict__ bias, void* __restrict__ Cout,
    int M, int K)
{
  constexpr int MT = TM / 16;
  constexpr int AH = TM * 32;
  constexpr int BH = 8192;
  __shared__ ushort smem[2 * AH + 2 * BH];
  const int tid  = threadIdx.x;
  const int lane = tid & 63, wave = tid >> 6;
  const int wn   = wave * 64;
  const int lrow = lane & 15, lgrp = lane >> 4;
  const long brow = (long)blockIdx.x * TM;
  const int NT = K >> 5;

  const float*  Af = (const float*)Ain;
  const ushort* A16 = (const ushort*)Ain;

  f32x4 acc[MT][4] = {};

  int arow, as_;
  if constexpr (TM == 64) { arow = tid >> 2; as_ = tid & 3; }
  else                    { arow = tid >> 3; as_ = tid & 7; }

  ushort* Acur = smem;
  ushort* Anxt = smem + AH;
  ushort* Bcur = smem + 2 * AH;
  ushort* Bnxt = smem + 2 * AH + BH;

#define LOAD_A(R0, R1, RU, tt)                                                  \
  if constexpr (ABF16) {                                                        \
    RU = *(const uint2*)&A16[(size_t)(brow + arow) * K + (tt) * 32 + as_ * 4];  \
  } else if constexpr (TM == 64) {                                              \
    const float* ap_ = &Af[(size_t)(brow + arow) * K] + (tt) * 32 + as_ * 8;    \
    R0 = *(const float4*)ap_;                                                   \
    R1 = *(const float4*)(ap_ + 4);                                             \
  } else {                                                                      \
    const int g_ = as_ >> 1, h_ = (as_ & 1) * 4;                                \
    R0 = *(const float4*)&Af[(size_t)(brow + arow) * K + (tt) * 32 + g_ * 8 + h_]; \
  }

#define STORE_A(R0, R1, RU, DST)                                                \
  if constexpr (ABF16) {                                                        \
    const int g_ = as_ >> 1, h_ = (as_ & 1) * 4;                                \
    *(uint2*)&(DST)[aidx(arow, g_ ^ fr(arow)) + h_] = RU;                       \
  } else if constexpr (TM == 64) {                                              \
    const float v_[8] = {R0.x, R0.y, R0.z, R0.w, R1.x, R1.y, R1.z, R1.w};       \
    ushort hh_[8];                                                              \
    _Pragma("unroll")                                                           \
    for (int j_ = 0; j_ < 8; ++j_) hh_[j_] = f2bf_rn(v_[j_]);                   \
    uint4 hv_ = {pack2(hh_[0],hh_[1]), pack2(hh_[2],hh_[3]),                    \
                 pack2(hh_[4],hh_[5]), pack2(hh_[6],hh_[7])};                   \
    *(uint4*)&(DST)[aidx(arow, as_ ^ fr(arow))] = hv_;                          \
  } else {                                                                      \
    const int g_ = as_ >> 1, h_ = (as_ & 1) * 4;                                \
    ushort hh_[4] = {f2bf_rn(R0.x), f2bf_rn(R0.y), f2bf_rn(R0.z), f2bf_rn(R0.w)}; \
    uint2 hv_ = {pack2(hh_[0],hh_[1]), pack2(hh_[2],hh_[3])};                   \
    *(uint2*)&(DST)[aidx(arow, g_ ^ fr(arow)) + h_] = hv_;                      \
  }

  // ---- prologue: B(0) glds, A(0) stage direct, A(1) -> reg set b ----
#pragma unroll
  for (int i = 0; i < 4; ++i)
    __builtin_amdgcn_global_load_lds(
        (const AS1 void*)(Bprep + wave * 2048 + (lane + 64 * i) * 8),
        (AS3 void*)(Bcur + wave * 2048 + (lane + 64 * i) * 8), 16, 0, 0);
  {
    float4 t0 = {}, t1 = {};
    uint2  tu = {};
    LOAD_A(t0, t1, tu, 0);
    STORE_A(t0, t1, tu, Acur);
  }
  float4 ra0 = {}, ra1 = {}, rb0 = {}, rb1 = {};
  uint2  rau = {}, rbu = {};
  if (1 < NT) { LOAD_A(rb0, rb1, rbu, 1); }
  __syncthreads();

  for (int t = 0; t < NT; t += 2) {
    // ======== body(t): regs-b hold A(t+1); regs-a free ========
    if (t + 1 < NT) {
#pragma unroll
      for (int i = 0; i < 4; ++i)
        __builtin_amdgcn_global_load_lds(
            (const AS1 void*)(Bprep + (size_t)(t + 1) * BH + wave * 2048 + (lane + 64 * i) * 8),
            (AS3 void*)(Bnxt + wave * 2048 + (lane + 64 * i) * 8), 16, 0, 0);
    }
    if (t + 2 < NT) { LOAD_A(ra0, ra1, rau, t + 2); }

    {
      bf16x8 ah[MT];
#pragma unroll
      for (int mt = 0; mt < MT; ++mt) {
        const int r = mt * 16 + lrow;
        ah[mt] = *(const bf16x8*)&Acur[aidx(r, lgrp ^ fr(r))];
      }
#pragma unroll
      for (int nt = 0; nt < 4; ++nt) {
        const int r = wn + nt * 16 + lrow;
        const bf16x8 b = *(const bf16x8*)&Bcur[aidx(r, lgrp ^ fr(r))];
#pragma unroll
        for (int mt = 0; mt < MT; ++mt)
          acc[mt][nt] = __builtin_amdgcn_mfma_f32_16x16x32_bf16(ah[mt], b, acc[mt][nt], 0, 0, 0);
      }
    }
    if (t + 1 < NT) { STORE_A(rb0, rb1, rbu, Anxt); }
    __syncthreads();
    { ushort* tp = Acur; Acur = Anxt; Anxt = tp;
      tp = Bcur; Bcur = Bnxt; Bnxt = tp; }

    // ======== body(t+1): regs-a hold A(t+2); regs-b free ========
    if (t + 1 >= NT) break;
    if (t + 2 < NT) {
#pragma unroll
      for (int i = 0; i < 4; ++i)
        __builtin_amdgcn_global_load_lds(
            (const AS1 void*)(Bprep + (size_t)(t + 2) * BH + wave * 2048 + (lane + 64 * i) * 8),
            (AS3 void*)(Bnxt + wave * 2048 + (lane + 64 * i) * 8), 16, 0, 0);
    }
    if (t + 3 < NT) { LOAD_A(rb0, rb1, rbu, t + 3); }

    {
      bf16x8 ah[MT];
#pragma unroll
      for (int mt = 0; mt < MT; ++mt) {
        const int r = mt * 16 + lrow;
        ah[mt] = *(const bf16x8*)&Acur[aidx(r, lgrp ^ fr(r))];
      }
#pragma unroll
      for (int nt = 0; nt < 4; ++nt) {
        const int r = wn + nt * 16 + lrow;
        const bf16x8 b = *(const bf16x8*)&Bcur[aidx(r, lgrp ^ fr(r))];
#pragma unroll
        for (int mt = 0; mt < MT; ++mt)
          acc[mt][nt] = __builtin_amdgcn_mfma_f32_16x16x32_bf16(ah[mt], b, acc[mt][nt], 0, 0, 0);
      }
    }
    if (t + 2 < NT) { STORE_A(ra0, ra1, rau, Anxt); }
    __syncthreads();
    { ushort* tp = Acur; Acur = Anxt; Anxt = tp;
      tp = Bcur; Bcur = Bnxt; Bnxt = tp; }
  }
#undef LOAD_A
#undef STORE_A

  // ---- epilogue ----
  float bb[4];
#pragma unroll
  for (int nt = 0; nt < 4; ++nt) bb[nt] = bias[wn + nt * 16 + lrow];

  if constexpr (CBF16) {
    ushort* Cb = (ushort*)Cout;
    ushort* ctu = smem;
#pragma unroll
    for (int h = 0; h < TM / 32; ++h) {
      __syncthreads();
#pragma unroll
      for (int m2 = 0; m2 < 2; ++m2) {
        const int mt = h * 2 + m2;
        const int lr0 = m2 * 16 + lgrp * 4;
#pragma unroll
        for (int nt = 0; nt < 4; ++nt) {
          const int col = wn + nt * 16 + lrow;
#pragma unroll
          for (int j = 0; j < 4; ++j)
            ctu[(lr0 + j) * 264 + col] = f2bf_rn(acc[mt][nt][j] + bb[nt]);
        }
      }
      __syncthreads();
#pragma unroll
      for (int i = 0; i < 4; ++i) {
        const int idx = i * 256 + tid, r = idx >> 5, c16 = (idx & 31) * 8;
        *(uint4*)&Cb[(size_t)(brow + h * 32 + r) * 256 + c16] =
            *(const uint4*)&ctu[r * 264 + c16];
      }
    }
  } else {
    float* C = (float*)Cout;
    float* ctile = (float*)smem;
#pragma unroll
    for (int h = 0; h < MT; ++h) {
      __syncthreads();
#pragma unroll
      for (int nt = 0; nt < 4; ++nt) {
        const int col = wn + nt * 16 + lrow;
#pragma unroll
        for (int j = 0; j < 4; ++j)
          ctile[(lgrp * 4 + j) * 260 + col] = acc[h][nt][j] + bb[nt];
      }
      __syncthreads();
#pragma unroll
      for (int i = 0; i < 4; ++i) {
        const int idx = i * 256 + tid, r = idx >> 6, c4 = (idx & 63) << 2;
        *(float4*)&C[(size_t)(brow + h * 16 + r) * 256 + c4] =
            *(const float4*)&ctile[r * 260 + c4];
      }
    }
  }
}

// ---------------------------------------------------------------------------
// proj as split-3 MFMA mini-GEMM (r18, verified). pobuf[BQ,128] =
// query @ [W_off|W_attn|0] + bias. 4-iter B staging (= exactly BH).
// ---------------------------------------------------------------------------
__global__ __launch_bounds__(256, 2) void proj_gemm(
    const float* __restrict__ query,
    const ushort* __restrict__ Bprep,   // [8][8192] pre-swizzled (hi/lo)
    const float* __restrict__ b_off, const float* __restrict__ b_attn,
    float* __restrict__ pobuf)
{
  constexpr int AH = 32 * 64;
  constexpr int BH = 8192;
  __shared__ ushort smem[2 * AH + 2 * BH];
  const int tid  = threadIdx.x;
  const int lane = tid & 63, wave = tid >> 6;
  const int wm   = (wave >> 1) * 16;
  const int wn   = (wave & 1) * 64;
  const int lrow = lane & 15, lgrp = lane >> 4;
  const long brow = (long)blockIdx.x * 32;

  f32x4 acc[4] = {};

  const int arow = tid >> 3, as_ = tid & 7;
  const float* Abase = &query[(size_t)(brow + arow) * 256];

  ushort* Acur = smem;
  ushort* Anxt = smem + AH;
  ushort* Bcur = smem + 2 * AH;
  ushort* Bnxt = smem + 2 * AH + BH;

#pragma unroll
  for (int i = 0; i < 4; ++i)
    __builtin_amdgcn_global_load_lds(
        (const AS1 void*)(Bprep + wave * 2048 + (lane + 64 * i) * 8),
        (AS3 void*)(Bcur + wave * 2048 + (lane + 64 * i) * 8), 16, 0, 0);
  {
    const int g = as_ >> 1, half = (as_ & 1) * 4;
    float4 a0 = *(const float4*)(Abase + g * 8 + half);
    ushort h[4], l[4];
#pragma unroll
    for (int j = 0; j < 4; ++j) {
      const float v = ((const float*)&a0)[j];
      h[j] = f2bf_rn(v);
      l[j] = f2bf_rn(v - bf2f(h[j]));
    }
    *(uint2*)&Acur[gidx8(arow, g) + half]     = uint2{pack2(h[0],h[1]), pack2(h[2],h[3])};
    *(uint2*)&Acur[gidx8(arow, g + 4) + half] = uint2{pack2(l[0],l[1]), pack2(l[2],l[3])};
  }
  __syncthreads();

  for (int t = 0; t < 8; ++t) {
    const bool more = (t + 1 < 8);

    if (more) {
#pragma unroll
      for (int i = 0; i < 4; ++i)
        __builtin_amdgcn_global_load_lds(
            (const AS1 void*)(Bprep + (size_t)(t + 1) * BH + wave * 2048 + (lane + 64 * i) * 8),
            (AS3 void*)(Bnxt + wave * 2048 + (lane + 64 * i) * 8), 16, 0, 0);
    }

    float4 a0 = {};
    const int g = as_ >> 1, half = (as_ & 1) * 4;
    if (more)
      a0 = *(const float4*)(Abase + (t + 1) * 32 + g * 8 + half);

    const int ra = wm + lrow;
    const bf16x8 ah = *(const bf16x8*)&Acur[gidx8(ra, lgrp)];
    const bf16x8 al = *(const bf16x8*)&Acur[gidx8(ra, lgrp + 4)];
#pragma unroll
    for (int nt = 0; nt < 4; ++nt) {
      const int rb = wn + nt * 16 + lrow;
      const bf16x8 bh = *(const bf16x8*)&Bcur[gidx8(rb, lgrp)];
      const bf16x8 bl = *(const bf16x8*)&Bcur[gidx8(rb, lgrp + 4)];
      acc[nt] = __builtin_amdgcn_mfma_f32_16x16x32_bf16(ah, bh, acc[nt], 0, 0, 0);
      acc[nt] = __builtin_amdgcn_mfma_f32_16x16x32_bf16(ah, bl, acc[nt], 0, 0, 0);
      acc[nt] = __builtin_amdgcn_mfma_f32_16x16x32_bf16(al, bh, acc[nt], 0, 0, 0);
    }

    if (more) {
      ushort h[4], l[4];
#pragma unroll
      for (int j = 0; j < 4; ++j) {
        const float v = ((const float*)&a0)[j];
        h[j] = f2bf_rn(v);
        l[j] = f2bf_rn(v - bf2f(h[j]));
      }
      *(uint2*)&Anxt[gidx8(arow, g) + half]     = uint2{pack2(h[0],h[1]), pack2(h[2],h[3])};
      *(uint2*)&Anxt[gidx8(arow, g + 4) + half] = uint2{pack2(l[0],l[1]), pack2(l[2],l[3])};
    }

    __syncthreads();
    ushort* tp;
    tp = Acur; Acur = Anxt; Anxt = tp;
    tp = Bcur; Bcur = Bnxt; Bnxt = tp;
  }

  __syncthreads();
  float* ctile = (float*)smem;
#pragma unroll
  for (int nt = 0; nt < 4; ++nt) {
    const int col = wn + nt * 16 + lrow;
    const float bb = (col < 64) ? b_off[col] : (col < 96 ? b_attn[col - 64] : 0.0f);
#pragma unroll
    for (int j = 0; j < 4; ++j)
      ctile[(wm + lgrp * 4 + j) * 132 + col] = acc[nt][j] + bb;
  }
  __syncthreads();
#pragma unroll
  for (int i = 0; i < 4; ++i) {
    const int idx = i * 256 + tid, r = idx >> 5, c4 = (idx & 31) * 4;
    *(float4*)&pobuf[(size_t)(brow + r) * 128 + c4] = *(const float4*)&ctile[r * 132 + c4];
  }
}

// ---------------------------------------------------------------------------
// Weight prep (one launch): Wv/Wo -> 64-B-row bf16 hi-only tables (r15);
// Wcat = [W_off|W_attn|0] -> 128-B-row split hi/lo table for proj_gemm.
// ---------------------------------------------------------------------------
__global__ __launch_bounds__(256) void prep_wt3(
    const float* __restrict__ Wv, const float* __restrict__ Wo,
    const float* __restrict__ W_off, const float* __restrict__ W_attn,
    ushort* __restrict__ Bv, ushort* __restrict__ Bo, ushort* __restrict__ Bpo)
{
  const int gid = blockIdx.x * 256 + threadIdx.x;  // 0..196607
  if (gid < 131072) {
    const float* W = (gid < 65536) ? Wv : Wo;
    ushort* Bp     = (gid < 65536) ? Bv : Bo;
    const int pg = gid & 65535;
    const int t = pg >> 13;
    const int p = pg & 8191;
    const int r = p >> 5;
    const int q = p & 31;
    const int gpos = q >> 3;
    const int j = q & 7;
    const int g0 = gpos ^ ((r >> 1) & 3);
    const int k = t * 32 + g0 * 8 + j;
    Bp[pg] = f2bf_rn(W[(size_t)k * 256 + r]);
  } else {
    const int pg = gid - 131072;                   // 0..65535
    const int t = pg >> 13;
    const int p = pg & 8191;
    const int r = p >> 6;                          // col 0..127
    const int q = p & 63;
    const int gpos = q >> 3;
    const int j = q & 7;
    const int g0 = gpos ^ (r & 7);                 // 0-3 hi, 4-7 lo
    const int seg = g0 & 3, plane = g0 >> 2;
    const int k = t * 32 + seg * 8 + j;
    float w = 0.0f;
    if (r < 64)       w = W_off[(size_t)k * 64 + r];
    else if (r < 96)  w = W_attn[(size_t)k * 32 + (r - 64)];
    const ushort hi = f2bf_rn(w);
    Bpo[pg] = plane ? f2bf_rn(w - bf2f(hi)) : hi;
  }
}

// ---------------------------------------------------------------------------
// Softmax + bilinear sampling: batch-per-XCD swizzle, bf16 values/mid;
// r19: po loads vectorized (2x float4 offs + float4 logits + float2 refp).
// ---------------------------------------------------------------------------
__global__ __launch_bounds__(256, 8) void sample_kernel(
    const float* __restrict__ refp,    // [BQ,2]
    const float* __restrict__ pobuf,   // [BQ,128]: 0-63 offs, 64-95 logits
    const ushort* __restrict__ values, // [B,HW,256] bf16
    ushort* __restrict__ mid,          // [BQ,256] bf16
    const int* __restrict__ hptr, const int* __restrict__ wptr,
    int Q, int HW)
{
  const int lane = threadIdx.x & 63;
  const int cpx  = (int)gridDim.x >> 3;
  const int blk  = (blockIdx.x & 7) * cpx + (blockIdx.x >> 3);
  const int bq   = blk * 4 + (threadIdx.x >> 6);
  const int b    = bq / Q;
  const int W_   = *wptr;
  const int H_   = *hptr;
  const int h    = lane >> 3;
  const float* po = pobuf + (size_t)bq * 128;

  const float4 of0 = *(const float4*)&po[h * 8];
  const float4 of1 = *(const float4*)&po[h * 8 + 4];
  const float4 lg  = *(const float4*)&po[64 + h * 4];
  const float offx[4] = {of0.x, of0.z, of1.x, of1.z};
  const float offy[4] = {of0.y, of0.w, of1.y, of1.w};

  const float m  = fmaxf(fmaxf(lg.x, lg.y), fmaxf(lg.z, lg.w));
  const float e0 = __expf(lg.x - m), e1 = __expf(lg.y - m);
  const float e2 = __expf(lg.z - m), e3 = __expf(lg.w - m);
  const float inv = 1.0f / (e0 + e1 + e2 + e3);
  const float wt[4] = {e0 * inv, e1 * inv, e2 * inv, e3 * inv};

  const float2 rxy = *(const float2*)&refp[(size_t)bq * 2];
  const ushort* vb = values + (size_t)b * HW * 256;
  const int ch = lane * 4;

  f32x4 acc = {0.f, 0.f, 0.f, 0.f};
#pragma unroll
  for (int p = 0; p < NPOINTS; ++p) {
    float lx = rxy.x + offx[p];
    float ly = rxy.y + offy[p];
    lx = fminf(fmaxf(lx, 0.0f), 1.0f);
    ly = fminf(fmaxf(ly, 0.0f), 1.0f);
    const float sx = lx * (float)(W_ - 1);
    const float sy = ly * (float)(H_ - 1);
    int x0 = (int)floorf(sx);
    int y0 = (int)floorf(sy);
    x0 = min(max(x0, 0), W_ - 1);
    y0 = min(max(y0, 0), H_ - 1);
    const int x1 = min(x0 + 1, W_ - 1);
    const int y1 = min(y0 + 1, H_ - 1);
    const float wx1 = sx - (float)x0, wx0 = 1.0f - wx1;
    const float wy1 = sy - (float)y0, wy0 = 1.0f - wy1;

    const ushort4 g00 = *(const ushort4*)&vb[(size_t)(y0 * W_ + x0) * 256 + ch];
    const ushort4 g10 = *(const ushort4*)&vb[(size_t)(y0 * W_ + x1) * 256 + ch];
    const ushort4 g01 = *(const ushort4*)&vb[(size_t)(y1 * W_ + x0) * 256 + ch];
    const ushort4 g11 = *(const ushort4*)&vb[(size_t)(y1 * W_ + x1) * 256 + ch];

    const float w00 = wx0 * wy0, w10 = wx1 * wy0, w01 = wx0 * wy1, w11 = wx1 * wy1;
    const float wp = wt[p];
    const float f00[4] = {bf2f(g00.x), bf2f(g00.y), bf2f(g00.z), bf2f(g00.w)};
    const float f10[4] = {bf2f(g10.x), bf2f(g10.y), bf2f(g10.z), bf2f(g10.w)};
    const float f01[4] = {bf2f(g01.x), bf2f(g01.y), bf2f(g01.z), bf2f(g01.w)};
    const float f11[4] = {bf2f(g11.x), bf2f(g11.y), bf2f(g11.z), bf2f(g11.w)};
#pragma unroll
    for (int j = 0; j < 4; ++j)
      acc[j] += wp * (f00[j] * w00 + f01[j] * w01 + f10[j] * w10 + f11[j] * w11);
  }
  ushort4 mo;
  mo.x = f2bf_rn(acc[0]); mo.y = f2bf_rn(acc[1]);
  mo.z = f2bf_rn(acc[2]); mo.w = f2bf_rn(acc[3]);
  *(ushort4*)&mid[(size_t)bq * 256 + ch] = mo;
}

// ---------------------------------------------------------------------------
extern "C" void kernel_launch(void* const* d_in, const int* in_sizes, int n_in,
                              void* d_out, int out_size, void* d_ws, size_t ws_size,
                              hipStream_t stream)
{
  const float* query   = (const float*)d_in[0];
  const float* refp    = (const float*)d_in[1];
  const float* input_f = (const float*)d_in[2];
  const int*   hptr    = (const int*)d_in[3];
  const int*   wptr    = (const int*)d_in[4];
  const float* W_off   = (const float*)d_in[5];
  const float* b_off   = (const float*)d_in[6];
  const float* W_attn  = (const float*)d_in[7];
  const float* b_attn  = (const float*)d_in[8];
  const float* W_val   = (const float*)d_in[9];
  const float* b_val   = (const float*)d_in[10];
  const float* W_out   = (const float*)d_in[11];
  const float* b_out   = (const float*)d_in[12];
  float* out = (float*)d_out;

  const int D   = 256;
  const int BQ  = in_sizes[0] / D;   // 16384
  const int B   = 8;
  const int Q   = BQ / B;            // 2048
  const int BHW = in_sizes[2] / D;   // 80000
  const int HW  = BHW / B;           // 10000

  char* ws = (char*)d_ws;
  ushort* values = (ushort*)ws;                                 // bf16: 40.96 MB
  size_t o = (size_t)BHW * D * sizeof(ushort);
  float* pobuf  = (float*)(ws + o);  o += (size_t)BQ * 128 * sizeof(float);   // 8.39 MB
  ushort* midb  = (ushort*)(ws + o); o += (size_t)BQ * D * sizeof(ushort);    // 8.39 MB
  ushort* Bprep_val = (ushort*)(ws + o);  o += (size_t)8 * 8192 * sizeof(ushort);  // 128 KB
  ushort* Bprep_out = (ushort*)(ws + o);  o += (size_t)8 * 8192 * sizeof(ushort);  // 128 KB
  ushort* Bprep_po  = (ushort*)(ws + o);  o += (size_t)8 * 8192 * sizeof(ushort);  // 128 KB

  // 0. all weight preps in one launch
  prep_wt3<<<768, 256, 0, stream>>>(W_val, W_out, W_off, W_attn,
                                    Bprep_val, Bprep_out, Bprep_po);

  // 1. values(bf16) = input_flatten @ W_val + b_val
  gemm_bf16_n256<64, true, false><<<BHW / 64, 256, 0, stream>>>(
      input_f, Bprep_val, b_val, (void*)values, BHW, D);

  // 2. pobuf = query @ [W_off|W_attn|0] + bias  (split-3 MFMA)
  proj_gemm<<<BQ / 32, 256, 0, stream>>>(
      query, Bprep_po, b_off, b_attn, pobuf);

  // 3. softmax + bilinear sampling -> mid (bf16), batch-per-XCD swizzled
  sample_kernel<<<BQ / 4, 256, 0, stream>>>(
      refp, pobuf, values, midb, hptr, wptr, Q, HW);

  // 4. out = mid @ W_out + b_out  (fp32 C, bf16 A)
  gemm_bf16_n256<32, false, true><<<BQ / 32, 256, 0, stream>>>(
      (const void*)midb, Bprep_out, b_out, (void*)out, BQ, D);
}

// Round 20
// 66.646 us; speedup vs baseline: 2.2065x; 2.2065x over previous
//
#include <hip/hip_runtime.h>
#include <hip/hip_bf16.h>
#include <cstdint>

#define NHEADS 8
#define NPOINTS 4

typedef __bf16 bf16x8 __attribute__((ext_vector_type(8)));
typedef float f32x4 __attribute__((ext_vector_type(4)));

#define AS1 __attribute__((address_space(1)))
#define AS3 __attribute__((address_space(3)))

__device__ __forceinline__ ushort f2bf_rn(float x) {
  union { float f; uint32_t u; } c; c.f = x;
  uint32_t r = c.u + 0x7fffu + ((c.u >> 16) & 1u);
  return (ushort)(r >> 16);
}
__device__ __forceinline__ float bf2f(ushort h) {
  union { uint32_t u; float f; } c; c.u = ((uint32_t)h) << 16; return c.f;
}
__device__ __forceinline__ uint pack2(ushort a, ushort b) {
  return (uint)a | ((uint)b << 16);
}

// 64-B-row layout (r15, verified): 4 granules of 16 B, pos = seg ^ fr(row).
__device__ __forceinline__ int fr(int row) { return (row >> 1) & 3; }
__device__ __forceinline__ int aidx(int row, int gpos) { return row * 32 + gpos * 8; }

// 128-B-row split layout (r5-r13, verified): 8 granules, 0-3 hi / 4-7 lo,
// granule pos XOR-swizzled by (row&7).
__device__ __forceinline__ int gidx8(int row, int g0) {
  return row * 64 + ((g0 ^ (row & 7)) << 3);
}

// ---------------------------------------------------------------------------
// Pure-bf16 GEMM, N=256 — EXACT r18 structure (best measured: 66.6 total;
// r19's 2-deep prefetch rewrite regressed 2.3x and is reverted).
// B hi-only bf16, A+B double-buffered, B(t+1) glds a full step before the
// draining sync. BK=32. ABF16: A arrives bf16 -> A-stage is a uint2 copy.
// LDS = 2*(TM*64B) + 2*16KB = 40 KB @ TM=64 -> 4 blocks/CU.
// ---------------------------------------------------------------------------
template<int TM, bool CBF16, bool ABF16>
__global__ __launch_bounds__(256, 4) void gemm_bf16_n256(
    const void* __restrict__ Ain,
    const ushort* __restrict__ Bprep,   // [K/32][8192] pre-swizzled ushorts
    const float* __restrict__ bias, void* __restrict__ Cout,
    int M, int K)
{
  constexpr int MT = TM / 16;
  constexpr int AH = TM * 32;
  constexpr int BH = 8192;
  __shared__ ushort smem[2 * AH + 2 * BH];
  const int tid  = threadIdx.x;
  const int lane = tid & 63, wave = tid >> 6;
  const int wn   = wave * 64;
  const int lrow = lane & 15, lgrp = lane >> 4;
  const long brow = (long)blockIdx.x * TM;
  const int NT = K >> 5;

  const float*  Af = (const float*)Ain;
  const ushort* A16 = (const ushort*)Ain;

  f32x4 acc[MT][4] = {};

  int arow, as_;
  if constexpr (TM == 64) { arow = tid >> 2; as_ = tid & 3; }
  else                    { arow = tid >> 3; as_ = tid & 7; }

  ushort* Acur = smem;
  ushort* Anxt = smem + AH;
  ushort* Bcur = smem + 2 * AH;
  ushort* Bnxt = smem + 2 * AH + BH;

  // ---- prologue ----
#pragma unroll
  for (int i = 0; i < 4; ++i)
    __builtin_amdgcn_global_load_lds(
        (const AS1 void*)(Bprep + wave * 2048 + (lane + 64 * i) * 8),
        (AS3 void*)(Bcur + wave * 2048 + (lane + 64 * i) * 8), 16, 0, 0);
  if constexpr (ABF16) {
    uint2 av = *(const uint2*)&A16[(size_t)(brow + arow) * K + as_ * 4];
    const int g = as_ >> 1, half = (as_ & 1) * 4;
    *(uint2*)&Acur[aidx(arow, g ^ fr(arow)) + half] = av;
  } else if constexpr (TM == 64) {
    const float* ap = &Af[(size_t)(brow + arow) * K] + as_ * 8;
    float4 a0 = *(const float4*)ap, a1 = *(const float4*)(ap + 4);
    const float v[8] = {a0.x, a0.y, a0.z, a0.w, a1.x, a1.y, a1.z, a1.w};
    ushort h[8];
#pragma unroll
    for (int j = 0; j < 8; ++j) h[j] = f2bf_rn(v[j]);
    uint4 hv = {pack2(h[0],h[1]), pack2(h[2],h[3]), pack2(h[4],h[5]), pack2(h[6],h[7])};
    *(uint4*)&Acur[aidx(arow, as_ ^ fr(arow))] = hv;
  } else {
    const int g = as_ >> 1, half = (as_ & 1) * 4;
    float4 a0 = *(const float4*)&Af[(size_t)(brow + arow) * K + g * 8 + half];
    ushort h[4] = {f2bf_rn(a0.x), f2bf_rn(a0.y), f2bf_rn(a0.z), f2bf_rn(a0.w)};
    uint2 hv = {pack2(h[0],h[1]), pack2(h[2],h[3])};
    *(uint2*)&Acur[aidx(arow, g ^ fr(arow)) + half] = hv;
  }
  __syncthreads();

  for (int t = 0; t < NT; ++t) {
    const bool more = (t + 1 < NT);

    if (more) {
#pragma unroll
      for (int i = 0; i < 4; ++i)
        __builtin_amdgcn_global_load_lds(
            (const AS1 void*)(Bprep + (size_t)(t + 1) * BH + wave * 2048 + (lane + 64 * i) * 8),
            (AS3 void*)(Bnxt + wave * 2048 + (lane + 64 * i) * 8), 16, 0, 0);
    }

    float4 a0 = {}, a1 = {};
    uint2 au = {};
    if (more) {
      if constexpr (ABF16) {
        au = *(const uint2*)&A16[(size_t)(brow + arow) * K + (t + 1) * 32 + as_ * 4];
      } else if constexpr (TM == 64) {
        const float* ap = &Af[(size_t)(brow + arow) * K] + (t + 1) * 32 + as_ * 8;
        a0 = *(const float4*)ap;
        a1 = *(const float4*)(ap + 4);
      } else {
        const int g = as_ >> 1, half = (as_ & 1) * 4;
        a0 = *(const float4*)&Af[(size_t)(brow + arow) * K + (t + 1) * 32 + g * 8 + half];
      }
    }

    bf16x8 ah[MT];
#pragma unroll
    for (int mt = 0; mt < MT; ++mt) {
      const int r = mt * 16 + lrow;
      ah[mt] = *(const bf16x8*)&Acur[aidx(r, lgrp ^ fr(r))];
    }
#pragma unroll
    for (int nt = 0; nt < 4; ++nt) {
      const int r = wn + nt * 16 + lrow;
      const bf16x8 b = *(const bf16x8*)&Bcur[aidx(r, lgrp ^ fr(r))];
#pragma unroll
      for (int mt = 0; mt < MT; ++mt)
        acc[mt][nt] = __builtin_amdgcn_mfma_f32_16x16x32_bf16(ah[mt], b, acc[mt][nt], 0, 0, 0);
    }

    if (more) {
      if constexpr (ABF16) {
        const int g = as_ >> 1, half = (as_ & 1) * 4;
        *(uint2*)&Anxt[aidx(arow, g ^ fr(arow)) + half] = au;
      } else if constexpr (TM == 64) {
        const float v[8] = {a0.x, a0.y, a0.z, a0.w, a1.x, a1.y, a1.z, a1.w};
        ushort h[8];
#pragma unroll
        for (int j = 0; j < 8; ++j) h[j] = f2bf_rn(v[j]);
        uint4 hv = {pack2(h[0],h[1]), pack2(h[2],h[3]), pack2(h[4],h[5]), pack2(h[6],h[7])};
        *(uint4*)&Anxt[aidx(arow, as_ ^ fr(arow))] = hv;
      } else {
        const int g = as_ >> 1, half = (as_ & 1) * 4;
        ushort h[4] = {f2bf_rn(a0.x), f2bf_rn(a0.y), f2bf_rn(a0.z), f2bf_rn(a0.w)};
        uint2 hv = {pack2(h[0],h[1]), pack2(h[2],h[3])};
        *(uint2*)&Anxt[aidx(arow, g ^ fr(arow)) + half] = hv;
      }
    }

    __syncthreads();
    ushort* tp;
    tp = Acur; Acur = Anxt; Anxt = tp;
    tp = Bcur; Bcur = Bnxt; Bnxt = tp;
  }

  // ---- epilogue ----
  float bb[4];
#pragma unroll
  for (int nt = 0; nt < 4; ++nt) bb[nt] = bias[wn + nt * 16 + lrow];

  if constexpr (CBF16) {
    ushort* Cb = (ushort*)Cout;
    ushort* ctu = smem;
#pragma unroll
    for (int h = 0; h < TM / 32; ++h) {
      __syncthreads();
#pragma unroll
      for (int m2 = 0; m2 < 2; ++m2) {
        const int mt = h * 2 + m2;
        const int lr0 = m2 * 16 + lgrp * 4;
#pragma unroll
        for (int nt = 0; nt < 4; ++nt) {
          const int col = wn + nt * 16 + lrow;
#pragma unroll
          for (int j = 0; j < 4; ++j)
            ctu[(lr0 + j) * 264 + col] = f2bf_rn(acc[mt][nt][j] + bb[nt]);
        }
      }
      __syncthreads();
#pragma unroll
      for (int i = 0; i < 4; ++i) {
        const int idx = i * 256 + tid, r = idx >> 5, c16 = (idx & 31) * 8;
        *(uint4*)&Cb[(size_t)(brow + h * 32 + r) * 256 + c16] =
            *(const uint4*)&ctu[r * 264 + c16];
      }
    }
  } else {
    float* C = (float*)Cout;
    float* ctile = (float*)smem;
#pragma unroll
    for (int h = 0; h < MT; ++h) {
      __syncthreads();
#pragma unroll
      for (int nt = 0; nt < 4; ++nt) {
        const int col = wn + nt * 16 + lrow;
#pragma unroll
        for (int j = 0; j < 4; ++j)
          ctile[(lgrp * 4 + j) * 260 + col] = acc[h][nt][j] + bb[nt];
      }
      __syncthreads();
#pragma unroll
      for (int i = 0; i < 4; ++i) {
        const int idx = i * 256 + tid, r = idx >> 6, c4 = (idx & 63) << 2;
        *(float4*)&C[(size_t)(brow + h * 16 + r) * 256 + c4] =
            *(const float4*)&ctile[r * 260 + c4];
      }
    }
  }
}

// ---------------------------------------------------------------------------
// proj as split-3 MFMA mini-GEMM (r18, verified). pobuf[BQ,128] =
// query @ [W_off|W_attn|0] + bias. 4-iter B staging (= exactly BH).
// ---------------------------------------------------------------------------
__global__ __launch_bounds__(256, 2) void proj_gemm(
    const float* __restrict__ query,
    const ushort* __restrict__ Bprep,   // [8][8192] pre-swizzled (hi/lo)
    const float* __restrict__ b_off, const float* __restrict__ b_attn,
    float* __restrict__ pobuf)
{
  constexpr int AH = 32 * 64;
  constexpr int BH = 8192;
  __shared__ ushort smem[2 * AH + 2 * BH];
  const int tid  = threadIdx.x;
  const int lane = tid & 63, wave = tid >> 6;
  const int wm   = (wave >> 1) * 16;
  const int wn   = (wave & 1) * 64;
  const int lrow = lane & 15, lgrp = lane >> 4;
  const long brow = (long)blockIdx.x * 32;

  f32x4 acc[4] = {};

  const int arow = tid >> 3, as_ = tid & 7;
  const float* Abase = &query[(size_t)(brow + arow) * 256];

  ushort* Acur = smem;
  ushort* Anxt = smem + AH;
  ushort* Bcur = smem + 2 * AH;
  ushort* Bnxt = smem + 2 * AH + BH;

#pragma unroll
  for (int i = 0; i < 4; ++i)
    __builtin_amdgcn_global_load_lds(
        (const AS1 void*)(Bprep + wave * 2048 + (lane + 64 * i) * 8),
        (AS3 void*)(Bcur + wave * 2048 + (lane + 64 * i) * 8), 16, 0, 0);
  {
    const int g = as_ >> 1, half = (as_ & 1) * 4;
    float4 a0 = *(const float4*)(Abase + g * 8 + half);
    ushort h[4], l[4];
#pragma unroll
    for (int j = 0; j < 4; ++j) {
      const float v = ((const float*)&a0)[j];
      h[j] = f2bf_rn(v);
      l[j] = f2bf_rn(v - bf2f(h[j]));
    }
    *(uint2*)&Acur[gidx8(arow, g) + half]     = uint2{pack2(h[0],h[1]), pack2(h[2],h[3])};
    *(uint2*)&Acur[gidx8(arow, g + 4) + half] = uint2{pack2(l[0],l[1]), pack2(l[2],l[3])};
  }
  __syncthreads();

  for (int t = 0; t < 8; ++t) {
    const bool more = (t + 1 < 8);

    if (more) {
#pragma unroll
      for (int i = 0; i < 4; ++i)
        __builtin_amdgcn_global_load_lds(
            (const AS1 void*)(Bprep + (size_t)(t + 1) * BH + wave * 2048 + (lane + 64 * i) * 8),
            (AS3 void*)(Bnxt + wave * 2048 + (lane + 64 * i) * 8), 16, 0, 0);
    }

    float4 a0 = {};
    const int g = as_ >> 1, half = (as_ & 1) * 4;
    if (more)
      a0 = *(const float4*)(Abase + (t + 1) * 32 + g * 8 + half);

    const int ra = wm + lrow;
    const bf16x8 ah = *(const bf16x8*)&Acur[gidx8(ra, lgrp)];
    const bf16x8 al = *(const bf16x8*)&Acur[gidx8(ra, lgrp + 4)];
#pragma unroll
    for (int nt = 0; nt < 4; ++nt) {
      const int rb = wn + nt * 16 + lrow;
      const bf16x8 bh = *(const bf16x8*)&Bcur[gidx8(rb, lgrp)];
      const bf16x8 bl = *(const bf16x8*)&Bcur[gidx8(rb, lgrp + 4)];
      acc[nt] = __builtin_amdgcn_mfma_f32_16x16x32_bf16(ah, bh, acc[nt], 0, 0, 0);
      acc[nt] = __builtin_amdgcn_mfma_f32_16x16x32_bf16(ah, bl, acc[nt], 0, 0, 0);
      acc[nt] = __builtin_amdgcn_mfma_f32_16x16x32_bf16(al, bh, acc[nt], 0, 0, 0);
    }

    if (more) {
      ushort h[4], l[4];
#pragma unroll
      for (int j = 0; j < 4; ++j) {
        const float v = ((const float*)&a0)[j];
        h[j] = f2bf_rn(v);
        l[j] = f2bf_rn(v - bf2f(h[j]));
      }
      *(uint2*)&Anxt[gidx8(arow, g) + half]     = uint2{pack2(h[0],h[1]), pack2(h[2],h[3])};
      *(uint2*)&Anxt[gidx8(arow, g + 4) + half] = uint2{pack2(l[0],l[1]), pack2(l[2],l[3])};
    }

    __syncthreads();
    ushort* tp;
    tp = Acur; Acur = Anxt; Anxt = tp;
    tp = Bcur; Bcur = Bnxt; Bnxt = tp;
  }

  __syncthreads();
  float* ctile = (float*)smem;
#pragma unroll
  for (int nt = 0; nt < 4; ++nt) {
    const int col = wn + nt * 16 + lrow;
    const float bb = (col < 64) ? b_off[col] : (col < 96 ? b_attn[col - 64] : 0.0f);
#pragma unroll
    for (int j = 0; j < 4; ++j)
      ctile[(wm + lgrp * 4 + j) * 132 + col] = acc[nt][j] + bb;
  }
  __syncthreads();
#pragma unroll
  for (int i = 0; i < 4; ++i) {
    const int idx = i * 256 + tid, r = idx >> 5, c4 = (idx & 31) * 4;
    *(float4*)&pobuf[(size_t)(brow + r) * 128 + c4] = *(const float4*)&ctile[r * 132 + c4];
  }
}

// ---------------------------------------------------------------------------
// Weight prep (one launch): Wv/Wo -> 64-B-row bf16 hi-only tables (r15);
// Wcat = [W_off|W_attn|0] -> 128-B-row split hi/lo table for proj_gemm.
// ---------------------------------------------------------------------------
__global__ __launch_bounds__(256) void prep_wt3(
    const float* __restrict__ Wv, const float* __restrict__ Wo,
    const float* __restrict__ W_off, const float* __restrict__ W_attn,
    ushort* __restrict__ Bv, ushort* __restrict__ Bo, ushort* __restrict__ Bpo)
{
  const int gid = blockIdx.x * 256 + threadIdx.x;  // 0..196607
  if (gid < 131072) {
    const float* W = (gid < 65536) ? Wv : Wo;
    ushort* Bp     = (gid < 65536) ? Bv : Bo;
    const int pg = gid & 65535;
    const int t = pg >> 13;
    const int p = pg & 8191;
    const int r = p >> 5;
    const int q = p & 31;
    const int gpos = q >> 3;
    const int j = q & 7;
    const int g0 = gpos ^ ((r >> 1) & 3);
    const int k = t * 32 + g0 * 8 + j;
    Bp[pg] = f2bf_rn(W[(size_t)k * 256 + r]);
  } else {
    const int pg = gid - 131072;                   // 0..65535
    const int t = pg >> 13;
    const int p = pg & 8191;
    const int r = p >> 6;                          // col 0..127
    const int q = p & 63;
    const int gpos = q >> 3;
    const int j = q & 7;
    const int g0 = gpos ^ (r & 7);                 // 0-3 hi, 4-7 lo
    const int seg = g0 & 3, plane = g0 >> 2;
    const int k = t * 32 + seg * 8 + j;
    float w = 0.0f;
    if (r < 64)       w = W_off[(size_t)k * 64 + r];
    else if (r < 96)  w = W_attn[(size_t)k * 32 + (r - 64)];
    const ushort hi = f2bf_rn(w);
    Bpo[pg] = plane ? f2bf_rn(w - bf2f(hi)) : hi;
  }
}

// ---------------------------------------------------------------------------
// Softmax + bilinear sampling: batch-per-XCD swizzle, bf16 values/mid;
// r20: po/refp loads vectorized (2x float4 offs + float4 logits + float2).
// ---------------------------------------------------------------------------
__global__ __launch_bounds__(256, 8) void sample_kernel(
    const float* __restrict__ refp,    // [BQ,2]
    const float* __restrict__ pobuf,   // [BQ,128]: 0-63 offs, 64-95 logits
    const ushort* __restrict__ values, // [B,HW,256] bf16
    ushort* __restrict__ mid,          // [BQ,256] bf16
    const int* __restrict__ hptr, const int* __restrict__ wptr,
    int Q, int HW)
{
  const int lane = threadIdx.x & 63;
  const int cpx  = (int)gridDim.x >> 3;
  const int blk  = (blockIdx.x & 7) * cpx + (blockIdx.x >> 3);
  const int bq   = blk * 4 + (threadIdx.x >> 6);
  const int b    = bq / Q;
  const int W_   = *wptr;
  const int H_   = *hptr;
  const int h    = lane >> 3;
  const float* po = pobuf + (size_t)bq * 128;

  const float4 of0 = *(const float4*)&po[h * 8];
  const float4 of1 = *(const float4*)&po[h * 8 + 4];
  const float4 lg  = *(const float4*)&po[64 + h * 4];
  const float offx[4] = {of0.x, of0.z, of1.x, of1.z};
  const float offy[4] = {of0.y, of0.w, of1.y, of1.w};

  const float m  = fmaxf(fmaxf(lg.x, lg.y), fmaxf(lg.z, lg.w));
  const float e0 = __expf(lg.x - m), e1 = __expf(lg.y - m);
  const float e2 = __expf(lg.z - m), e3 = __expf(lg.w - m);
  const float inv = 1.0f / (e0 + e1 + e2 + e3);
  const float wt[4] = {e0 * inv, e1 * inv, e2 * inv, e3 * inv};

  const float2 rxy = *(const float2*)&refp[(size_t)bq * 2];
  const ushort* vb = values + (size_t)b * HW * 256;
  const int ch = lane * 4;

  f32x4 acc = {0.f, 0.f, 0.f, 0.f};
#pragma unroll
  for (int p = 0; p < NPOINTS; ++p) {
    float lx = rxy.x + offx[p];
    float ly = rxy.y + offy[p];
    lx = fminf(fmaxf(lx, 0.0f), 1.0f);
    ly = fminf(fmaxf(ly, 0.0f), 1.0f);
    const float sx = lx * (float)(W_ - 1);
    const float sy = ly * (float)(H_ - 1);
    int x0 = (int)floorf(sx);
    int y0 = (int)floorf(sy);
    x0 = min(max(x0, 0), W_ - 1);
    y0 = min(max(y0, 0), H_ - 1);
    const int x1 = min(x0 + 1, W_ - 1);
    const int y1 = min(y0 + 1, H_ - 1);
    const float wx1 = sx - (float)x0, wx0 = 1.0f - wx1;
    const float wy1 = sy - (float)y0, wy0 = 1.0f - wy1;

    const ushort4 g00 = *(const ushort4*)&vb[(size_t)(y0 * W_ + x0) * 256 + ch];
    const ushort4 g10 = *(const ushort4*)&vb[(size_t)(y0 * W_ + x1) * 256 + ch];
    const ushort4 g01 = *(const ushort4*)&vb[(size_t)(y1 * W_ + x0) * 256 + ch];
    const ushort4 g11 = *(const ushort4*)&vb[(size_t)(y1 * W_ + x1) * 256 + ch];

    const float w00 = wx0 * wy0, w10 = wx1 * wy0, w01 = wx0 * wy1, w11 = wx1 * wy1;
    const float wp = wt[p];
    const float f00[4] = {bf2f(g00.x), bf2f(g00.y), bf2f(g00.z), bf2f(g00.w)};
    const float f10[4] = {bf2f(g10.x), bf2f(g10.y), bf2f(g10.z), bf2f(g10.w)};
    const float f01[4] = {bf2f(g01.x), bf2f(g01.y), bf2f(g01.z), bf2f(g01.w)};
    const float f11[4] = {bf2f(g11.x), bf2f(g11.y), bf2f(g11.z), bf2f(g11.w)};
#pragma unroll
    for (int j = 0; j < 4; ++j)
      acc[j] += wp * (f00[j] * w00 + f01[j] * w01 + f10[j] * w10 + f11[j] * w11);
  }
  ushort4 mo;
  mo.x = f2bf_rn(acc[0]); mo.y = f2bf_rn(acc[1]);
  mo.z = f2bf_rn(acc[2]); mo.w = f2bf_rn(acc[3]);
  *(ushort4*)&mid[(size_t)bq * 256 + ch] = mo;
}

// ---------------------------------------------------------------------------
extern "C" void kernel_launch(void* const* d_in, const int* in_sizes, int n_in,
                              void* d_out, int out_size, void* d_ws, size_t ws_size,
                              hipStream_t stream)
{
  const float* query   = (const float*)d_in[0];
  const float* refp    = (const float*)d_in[1];
  const float* input_f = (const float*)d_in[2];
  const int*   hptr    = (const int*)d_in[3];
  const int*   wptr    = (const int*)d_in[4];
  const float* W_off   = (const float*)d_in[5];
  const float* b_off   = (const float*)d_in[6];
  const float* W_attn  = (const float*)d_in[7];
  const float* b_attn  = (const float*)d_in[8];
  const float* W_val   = (const float*)d_in[9];
  const float* b_val   = (const float*)d_in[10];
  const float* W_out   = (const float*)d_in[11];
  const float* b_out   = (const float*)d_in[12];
  float* out = (float*)d_out;

  const int D   = 256;
  const int BQ  = in_sizes[0] / D;   // 16384
  const int B   = 8;
  const int Q   = BQ / B;            // 2048
  const int BHW = in_sizes[2] / D;   // 80000
  const int HW  = BHW / B;           // 10000

  char* ws = (char*)d_ws;
  ushort* values = (ushort*)ws;                                 // bf16: 40.96 MB
  size_t o = (size_t)BHW * D * sizeof(ushort);
  float* pobuf  = (float*)(ws + o);  o += (size_t)BQ * 128 * sizeof(float);   // 8.39 MB
  ushort* midb  = (ushort*)(ws + o); o += (size_t)BQ * D * sizeof(ushort);    // 8.39 MB
  ushort* Bprep_val = (ushort*)(ws + o);  o += (size_t)8 * 8192 * sizeof(ushort);  // 128 KB
  ushort* Bprep_out = (ushort*)(ws + o);  o += (size_t)8 * 8192 * sizeof(ushort);  // 128 KB
  ushort* Bprep_po  = (ushort*)(ws + o);  o += (size_t)8 * 8192 * sizeof(ushort);  // 128 KB

  // 0. all weight preps in one launch
  prep_wt3<<<768, 256, 0, stream>>>(W_val, W_out, W_off, W_attn,
                                    Bprep_val, Bprep_out, Bprep_po);

  // 1. values(bf16) = input_flatten @ W_val + b_val
  gemm_bf16_n256<64, true, false><<<BHW / 64, 256, 0, stream>>>(
      input_f, Bprep_val, b_val, (void*)values, BHW, D);

  // 2. pobuf = query @ [W_off|W_attn|0] + bias  (split-3 MFMA)
  proj_gemm<<<BQ / 32, 256, 0, stream>>>(
      query, Bprep_po, b_off, b_attn, pobuf);

  // 3. softmax + bilinear sampling -> mid (bf16), batch-per-XCD swizzled
  sample_kernel<<<BQ / 4, 256, 0, stream>>>(
      refp, pobuf, values, midb, hptr, wptr, Q, HW);

  // 4. out = mid @ W_out + b_out  (fp32 C, bf16 A)
  gemm_bf16_n256<32, false, true><<<BQ / 32, 256, 0, stream>>>(
      (const void*)midb, Bprep_out, b_out, (void*)out, BQ, D);
}

// Round 21
// 62.958 us; speedup vs baseline: 2.3358x; 1.0586x over previous
//
#include <hip/hip_runtime.h>
#include <hip/hip_bf16.h>
#include <cstdint>

#define NHEADS 8
#define NPOINTS 4

typedef __bf16 bf16x8 __attribute__((ext_vector_type(8)));
typedef float f32x4 __attribute__((ext_vector_type(4)));

#define AS1 __attribute__((address_space(1)))
#define AS3 __attribute__((address_space(3)))

__device__ __forceinline__ ushort f2bf_rn(float x) {
  union { float f; uint32_t u; } c; c.f = x;
  uint32_t r = c.u + 0x7fffu + ((c.u >> 16) & 1u);
  return (ushort)(r >> 16);
}
__device__ __forceinline__ float bf2f(ushort h) {
  union { uint32_t u; float f; } c; c.u = ((uint32_t)h) << 16; return c.f;
}
__device__ __forceinline__ uint pack2(ushort a, ushort b) {
  return (uint)a | ((uint)b << 16);
}

// 64-B-row layout (r15, verified): 4 granules of 16 B, pos = seg ^ fr(row).
__device__ __forceinline__ int fr(int row) { return (row >> 1) & 3; }
__device__ __forceinline__ int aidx(int row, int gpos) { return row * 32 + gpos * 8; }

// 128-B-row split layout (r5-r13, verified): 8 granules, 0-3 hi / 4-7 lo,
// granule pos XOR-swizzled by (row&7).
__device__ __forceinline__ int gidx8(int row, int g0) {
  return row * 64 + ((g0 ^ (row & 7)) << 3);
}

// ---------------------------------------------------------------------------
// Pure-bf16 GEMM core, N=256 — EXACT r18 structure (best measured).
// B hi-only bf16, A+B double-buffered, B(t+1) glds a full step before the
// draining sync. BK=32. ABF16: A arrives bf16 -> A-stage is a uint2 copy.
// LDS usage: 2*(TM*64B) + 2*16KB <= 40 KB.
// ---------------------------------------------------------------------------
template<int TM, bool CBF16, bool ABF16>
__device__ __forceinline__ void gemm_core(
    ushort* smem, int bid,
    const void* __restrict__ Ain,
    const ushort* __restrict__ Bprep,
    const float* __restrict__ bias, void* __restrict__ Cout,
    int K)
{
  constexpr int MT = TM / 16;
  constexpr int AH = TM * 32;
  constexpr int BH = 8192;
  const int tid  = threadIdx.x;
  const int lane = tid & 63, wave = tid >> 6;
  const int wn   = wave * 64;
  const int lrow = lane & 15, lgrp = lane >> 4;
  const long brow = (long)bid * TM;
  const int NT = K >> 5;

  const float*  Af = (const float*)Ain;
  const ushort* A16 = (const ushort*)Ain;

  f32x4 acc[MT][4] = {};

  int arow, as_;
  if constexpr (TM == 64) { arow = tid >> 2; as_ = tid & 3; }
  else                    { arow = tid >> 3; as_ = tid & 7; }

  ushort* Acur = smem;
  ushort* Anxt = smem + AH;
  ushort* Bcur = smem + 2 * AH;
  ushort* Bnxt = smem + 2 * AH + BH;

  // ---- prologue ----
#pragma unroll
  for (int i = 0; i < 4; ++i)
    __builtin_amdgcn_global_load_lds(
        (const AS1 void*)(Bprep + wave * 2048 + (lane + 64 * i) * 8),
        (AS3 void*)(Bcur + wave * 2048 + (lane + 64 * i) * 8), 16, 0, 0);
  if constexpr (ABF16) {
    uint2 av = *(const uint2*)&A16[(size_t)(brow + arow) * K + as_ * 4];
    const int g = as_ >> 1, half = (as_ & 1) * 4;
    *(uint2*)&Acur[aidx(arow, g ^ fr(arow)) + half] = av;
  } else if constexpr (TM == 64) {
    const float* ap = &Af[(size_t)(brow + arow) * K] + as_ * 8;
    float4 a0 = *(const float4*)ap, a1 = *(const float4*)(ap + 4);
    const float v[8] = {a0.x, a0.y, a0.z, a0.w, a1.x, a1.y, a1.z, a1.w};
    ushort h[8];
#pragma unroll
    for (int j = 0; j < 8; ++j) h[j] = f2bf_rn(v[j]);
    uint4 hv = {pack2(h[0],h[1]), pack2(h[2],h[3]), pack2(h[4],h[5]), pack2(h[6],h[7])};
    *(uint4*)&Acur[aidx(arow, as_ ^ fr(arow))] = hv;
  } else {
    const int g = as_ >> 1, half = (as_ & 1) * 4;
    float4 a0 = *(const float4*)&Af[(size_t)(brow + arow) * K + g * 8 + half];
    ushort h[4] = {f2bf_rn(a0.x), f2bf_rn(a0.y), f2bf_rn(a0.z), f2bf_rn(a0.w)};
    uint2 hv = {pack2(h[0],h[1]), pack2(h[2],h[3])};
    *(uint2*)&Acur[aidx(arow, g ^ fr(arow)) + half] = hv;
  }
  __syncthreads();

  for (int t = 0; t < NT; ++t) {
    const bool more = (t + 1 < NT);

    if (more) {
#pragma unroll
      for (int i = 0; i < 4; ++i)
        __builtin_amdgcn_global_load_lds(
            (const AS1 void*)(Bprep + (size_t)(t + 1) * BH + wave * 2048 + (lane + 64 * i) * 8),
            (AS3 void*)(Bnxt + wave * 2048 + (lane + 64 * i) * 8), 16, 0, 0);
    }

    float4 a0 = {}, a1 = {};
    uint2 au = {};
    if (more) {
      if constexpr (ABF16) {
        au = *(const uint2*)&A16[(size_t)(brow + arow) * K + (t + 1) * 32 + as_ * 4];
      } else if constexpr (TM == 64) {
        const float* ap = &Af[(size_t)(brow + arow) * K] + (t + 1) * 32 + as_ * 8;
        a0 = *(const float4*)ap;
        a1 = *(const float4*)(ap + 4);
      } else {
        const int g = as_ >> 1, half = (as_ & 1) * 4;
        a0 = *(const float4*)&Af[(size_t)(brow + arow) * K + (t + 1) * 32 + g * 8 + half];
      }
    }

    bf16x8 ah[MT];
#pragma unroll
    for (int mt = 0; mt < MT; ++mt) {
      const int r = mt * 16 + lrow;
      ah[mt] = *(const bf16x8*)&Acur[aidx(r, lgrp ^ fr(r))];
    }
#pragma unroll
    for (int nt = 0; nt < 4; ++nt) {
      const int r = wn + nt * 16 + lrow;
      const bf16x8 b = *(const bf16x8*)&Bcur[aidx(r, lgrp ^ fr(r))];
#pragma unroll
      for (int mt = 0; mt < MT; ++mt)
        acc[mt][nt] = __builtin_amdgcn_mfma_f32_16x16x32_bf16(ah[mt], b, acc[mt][nt], 0, 0, 0);
    }

    if (more) {
      if constexpr (ABF16) {
        const int g = as_ >> 1, half = (as_ & 1) * 4;
        *(uint2*)&Anxt[aidx(arow, g ^ fr(arow)) + half] = au;
      } else if constexpr (TM == 64) {
        const float v[8] = {a0.x, a0.y, a0.z, a0.w, a1.x, a1.y, a1.z, a1.w};
        ushort h[8];
#pragma unroll
        for (int j = 0; j < 8; ++j) h[j] = f2bf_rn(v[j]);
        uint4 hv = {pack2(h[0],h[1]), pack2(h[2],h[3]), pack2(h[4],h[5]), pack2(h[6],h[7])};
        *(uint4*)&Anxt[aidx(arow, as_ ^ fr(arow))] = hv;
      } else {
        const int g = as_ >> 1, half = (as_ & 1) * 4;
        ushort h[4] = {f2bf_rn(a0.x), f2bf_rn(a0.y), f2bf_rn(a0.z), f2bf_rn(a0.w)};
        uint2 hv = {pack2(h[0],h[1]), pack2(h[2],h[3])};
        *(uint2*)&Anxt[aidx(arow, g ^ fr(arow)) + half] = hv;
      }
    }

    __syncthreads();
    ushort* tp;
    tp = Acur; Acur = Anxt; Anxt = tp;
    tp = Bcur; Bcur = Bnxt; Bnxt = tp;
  }

  // ---- epilogue ----
  float bb[4];
#pragma unroll
  for (int nt = 0; nt < 4; ++nt) bb[nt] = bias[wn + nt * 16 + lrow];

  if constexpr (CBF16) {
    ushort* Cb = (ushort*)Cout;
    ushort* ctu = smem;
#pragma unroll
    for (int h = 0; h < TM / 32; ++h) {
      __syncthreads();
#pragma unroll
      for (int m2 = 0; m2 < 2; ++m2) {
        const int mt = h * 2 + m2;
        const int lr0 = m2 * 16 + lgrp * 4;
#pragma unroll
        for (int nt = 0; nt < 4; ++nt) {
          const int col = wn + nt * 16 + lrow;
#pragma unroll
          for (int j = 0; j < 4; ++j)
            ctu[(lr0 + j) * 264 + col] = f2bf_rn(acc[mt][nt][j] + bb[nt]);
        }
      }
      __syncthreads();
#pragma unroll
      for (int i = 0; i < 4; ++i) {
        const int idx = i * 256 + tid, r = idx >> 5, c16 = (idx & 31) * 8;
        *(uint4*)&Cb[(size_t)(brow + h * 32 + r) * 256 + c16] =
            *(const uint4*)&ctu[r * 264 + c16];
      }
    }
  } else {
    float* C = (float*)Cout;
    float* ctile = (float*)smem;
#pragma unroll
    for (int h = 0; h < MT; ++h) {
      __syncthreads();
#pragma unroll
      for (int nt = 0; nt < 4; ++nt) {
        const int col = wn + nt * 16 + lrow;
#pragma unroll
        for (int j = 0; j < 4; ++j)
          ctile[(lgrp * 4 + j) * 260 + col] = acc[h][nt][j] + bb[nt];
      }
      __syncthreads();
#pragma unroll
      for (int i = 0; i < 4; ++i) {
        const int idx = i * 256 + tid, r = idx >> 6, c4 = (idx & 63) << 2;
        *(float4*)&C[(size_t)(brow + h * 16 + r) * 256 + c4] =
            *(const float4*)&ctile[r * 260 + c4];
      }
    }
  }
}

// ---------------------------------------------------------------------------
// proj core: split-3 MFMA mini-GEMM (r18, verified). pobuf[BQ,128] =
// query @ [W_off|W_attn|0] + bias. 4-iter B staging (= exactly BH=8192).
// LDS usage: 2*4KB A + 2*16KB B = 40 KB.
// ---------------------------------------------------------------------------
__device__ __forceinline__ void proj_core(
    ushort* smem, int bid,
    const float* __restrict__ query,
    const ushort* __restrict__ Bprep,
    const float* __restrict__ b_off, const float* __restrict__ b_attn,
    float* __restrict__ pobuf)
{
  constexpr int AH = 32 * 64;
  constexpr int BH = 8192;
  const int tid  = threadIdx.x;
  const int lane = tid & 63, wave = tid >> 6;
  const int wm   = (wave >> 1) * 16;
  const int wn   = (wave & 1) * 64;
  const int lrow = lane & 15, lgrp = lane >> 4;
  const long brow = (long)bid * 32;

  f32x4 acc[4] = {};

  const int arow = tid >> 3, as_ = tid & 7;
  const float* Abase = &query[(size_t)(brow + arow) * 256];

  ushort* Acur = smem;
  ushort* Anxt = smem + AH;
  ushort* Bcur = smem + 2 * AH;
  ushort* Bnxt = smem + 2 * AH + BH;

#pragma unroll
  for (int i = 0; i < 4; ++i)
    __builtin_amdgcn_global_load_lds(
        (const AS1 void*)(Bprep + wave * 2048 + (lane + 64 * i) * 8),
        (AS3 void*)(Bcur + wave * 2048 + (lane + 64 * i) * 8), 16, 0, 0);
  {
    const int g = as_ >> 1, half = (as_ & 1) * 4;
    float4 a0 = *(const float4*)(Abase + g * 8 + half);
    ushort h[4], l[4];
#pragma unroll
    for (int j = 0; j < 4; ++j) {
      const float v = ((const float*)&a0)[j];
      h[j] = f2bf_rn(v);
      l[j] = f2bf_rn(v - bf2f(h[j]));
    }
    *(uint2*)&Acur[gidx8(arow, g) + half]     = uint2{pack2(h[0],h[1]), pack2(h[2],h[3])};
    *(uint2*)&Acur[gidx8(arow, g + 4) + half] = uint2{pack2(l[0],l[1]), pack2(l[2],l[3])};
  }
  __syncthreads();

  for (int t = 0; t < 8; ++t) {
    const bool more = (t + 1 < 8);

    if (more) {
#pragma unroll
      for (int i = 0; i < 4; ++i)
        __builtin_amdgcn_global_load_lds(
            (const AS1 void*)(Bprep + (size_t)(t + 1) * BH + wave * 2048 + (lane + 64 * i) * 8),
            (AS3 void*)(Bnxt + wave * 2048 + (lane + 64 * i) * 8), 16, 0, 0);
    }

    float4 a0 = {};
    const int g = as_ >> 1, half = (as_ & 1) * 4;
    if (more)
      a0 = *(const float4*)(Abase + (t + 1) * 32 + g * 8 + half);

    const int ra = wm + lrow;
    const bf16x8 ah = *(const bf16x8*)&Acur[gidx8(ra, lgrp)];
    const bf16x8 al = *(const bf16x8*)&Acur[gidx8(ra, lgrp + 4)];
#pragma unroll
    for (int nt = 0; nt < 4; ++nt) {
      const int rb = wn + nt * 16 + lrow;
      const bf16x8 bh = *(const bf16x8*)&Bcur[gidx8(rb, lgrp)];
      const bf16x8 bl = *(const bf16x8*)&Bcur[gidx8(rb, lgrp + 4)];
      acc[nt] = __builtin_amdgcn_mfma_f32_16x16x32_bf16(ah, bh, acc[nt], 0, 0, 0);
      acc[nt] = __builtin_amdgcn_mfma_f32_16x16x32_bf16(ah, bl, acc[nt], 0, 0, 0);
      acc[nt] = __builtin_amdgcn_mfma_f32_16x16x32_bf16(al, bh, acc[nt], 0, 0, 0);
    }

    if (more) {
      ushort h[4], l[4];
#pragma unroll
      for (int j = 0; j < 4; ++j) {
        const float v = ((const float*)&a0)[j];
        h[j] = f2bf_rn(v);
        l[j] = f2bf_rn(v - bf2f(h[j]));
      }
      *(uint2*)&Anxt[gidx8(arow, g) + half]     = uint2{pack2(h[0],h[1]), pack2(h[2],h[3])};
      *(uint2*)&Anxt[gidx8(arow, g + 4) + half] = uint2{pack2(l[0],l[1]), pack2(l[2],l[3])};
    }

    __syncthreads();
    ushort* tp;
    tp = Acur; Acur = Anxt; Anxt = tp;
    tp = Bcur; Bcur = Bnxt; Bnxt = tp;
  }

  __syncthreads();
  float* ctile = (float*)smem;
#pragma unroll
  for (int nt = 0; nt < 4; ++nt) {
    const int col = wn + nt * 16 + lrow;
    const float bb = (col < 64) ? b_off[col] : (col < 96 ? b_attn[col - 64] : 0.0f);
#pragma unroll
    for (int j = 0; j < 4; ++j)
      ctile[(wm + lgrp * 4 + j) * 132 + col] = acc[nt][j] + bb;
  }
  __syncthreads();
#pragma unroll
  for (int i = 0; i < 4; ++i) {
    const int idx = i * 256 + tid, r = idx >> 5, c4 = (idx & 31) * 4;
    *(float4*)&pobuf[(size_t)(brow + r) * 128 + c4] = *(const float4*)&ctile[r * 132 + c4];
  }
}

// ---------------------------------------------------------------------------
// r21: FUSED launch — proj (blocks 0..npo-1) + gemm1 (blocks npo..): the two
// are independent (both depend only on prep); proj's 512 blocks fill gemm1's
// latency holes instead of a serial ~3.5 µs slot. Both paths use 40 KB LDS.
// ---------------------------------------------------------------------------
__global__ __launch_bounds__(256, 4) void fused_g1_proj(
    const float* __restrict__ input_f, const ushort* __restrict__ Bprep_val,
    const float* __restrict__ b_val, ushort* __restrict__ values,
    const float* __restrict__ query, const ushort* __restrict__ Bprep_po,
    const float* __restrict__ b_off, const float* __restrict__ b_attn,
    float* __restrict__ pobuf, int npo)
{
  __shared__ ushort smem[20480];   // 40 KB, shared by both paths
  const int bid = blockIdx.x;
  if (bid < npo) {
    proj_core(smem, bid, query, Bprep_po, b_off, b_attn, pobuf);
  } else {
    gemm_core<64, true, false>(smem, bid - npo, (const void*)input_f,
                               Bprep_val, b_val, (void*)values, 256);
  }
}

// gemm2 standalone (depends on sample's output).
__global__ __launch_bounds__(256, 4) void gemm2_kernel(
    const ushort* __restrict__ midb, const ushort* __restrict__ Bprep_out,
    const float* __restrict__ b_out, float* __restrict__ out)
{
  __shared__ ushort smem[20480];
  gemm_core<32, false, true>(smem, blockIdx.x, (const void*)midb,
                             Bprep_out, b_out, (void*)out, 256);
}

// ---------------------------------------------------------------------------
// Weight prep (one launch): Wv/Wo -> 64-B-row bf16 hi-only tables (r15);
// Wcat = [W_off|W_attn|0] -> 128-B-row split hi/lo table for proj.
// ---------------------------------------------------------------------------
__global__ __launch_bounds__(256) void prep_wt3(
    const float* __restrict__ Wv, const float* __restrict__ Wo,
    const float* __restrict__ W_off, const float* __restrict__ W_attn,
    ushort* __restrict__ Bv, ushort* __restrict__ Bo, ushort* __restrict__ Bpo)
{
  const int gid = blockIdx.x * 256 + threadIdx.x;  // 0..196607
  if (gid < 131072) {
    const float* W = (gid < 65536) ? Wv : Wo;
    ushort* Bp     = (gid < 65536) ? Bv : Bo;
    const int pg = gid & 65535;
    const int t = pg >> 13;
    const int p = pg & 8191;
    const int r = p >> 5;
    const int q = p & 31;
    const int gpos = q >> 3;
    const int j = q & 7;
    const int g0 = gpos ^ ((r >> 1) & 3);
    const int k = t * 32 + g0 * 8 + j;
    Bp[pg] = f2bf_rn(W[(size_t)k * 256 + r]);
  } else {
    const int pg = gid - 131072;                   // 0..65535
    const int t = pg >> 13;
    const int p = pg & 8191;
    const int r = p >> 6;                          // col 0..127
    const int q = p & 63;
    const int gpos = q >> 3;
    const int j = q & 7;
    const int g0 = gpos ^ (r & 7);                 // 0-3 hi, 4-7 lo
    const int seg = g0 & 3, plane = g0 >> 2;
    const int k = t * 32 + seg * 8 + j;
    float w = 0.0f;
    if (r < 64)       w = W_off[(size_t)k * 64 + r];
    else if (r < 96)  w = W_attn[(size_t)k * 32 + (r - 64)];
    const ushort hi = f2bf_rn(w);
    Bpo[pg] = plane ? f2bf_rn(w - bf2f(hi)) : hi;
  }
}

// ---------------------------------------------------------------------------
// Softmax + bilinear sampling: batch-per-XCD swizzle, bf16 values/mid,
// vectorized po/refp loads.
// ---------------------------------------------------------------------------
__global__ __launch_bounds__(256, 8) void sample_kernel(
    const float* __restrict__ refp,    // [BQ,2]
    const float* __restrict__ pobuf,   // [BQ,128]: 0-63 offs, 64-95 logits
    const ushort* __restrict__ values, // [B,HW,256] bf16
    ushort* __restrict__ mid,          // [BQ,256] bf16
    const int* __restrict__ hptr, const int* __restrict__ wptr,
    int Q, int HW)
{
  const int lane = threadIdx.x & 63;
  const int cpx  = (int)gridDim.x >> 3;
  const int blk  = (blockIdx.x & 7) * cpx + (blockIdx.x >> 3);
  const int bq   = blk * 4 + (threadIdx.x >> 6);
  const int b    = bq / Q;
  const int W_   = *wptr;
  const int H_   = *hptr;
  const int h    = lane >> 3;
  const float* po = pobuf + (size_t)bq * 128;

  const float4 of0 = *(const float4*)&po[h * 8];
  const float4 of1 = *(const float4*)&po[h * 8 + 4];
  const float4 lg  = *(const float4*)&po[64 + h * 4];
  const float offx[4] = {of0.x, of0.z, of1.x, of1.z};
  const float offy[4] = {of0.y, of0.w, of1.y, of1.w};

  const float m  = fmaxf(fmaxf(lg.x, lg.y), fmaxf(lg.z, lg.w));
  const float e0 = __expf(lg.x - m), e1 = __expf(lg.y - m);
  const float e2 = __expf(lg.z - m), e3 = __expf(lg.w - m);
  const float inv = 1.0f / (e0 + e1 + e2 + e3);
  const float wt[4] = {e0 * inv, e1 * inv, e2 * inv, e3 * inv};

  const float2 rxy = *(const float2*)&refp[(size_t)bq * 2];
  const ushort* vb = values + (size_t)b * HW * 256;
  const int ch = lane * 4;

  f32x4 acc = {0.f, 0.f, 0.f, 0.f};
#pragma unroll
  for (int p = 0; p < NPOINTS; ++p) {
    float lx = rxy.x + offx[p];
    float ly = rxy.y + offy[p];
    lx = fminf(fmaxf(lx, 0.0f), 1.0f);
    ly = fminf(fmaxf(ly, 0.0f), 1.0f);
    const float sx = lx * (float)(W_ - 1);
    const float sy = ly * (float)(H_ - 1);
    int x0 = (int)floorf(sx);
    int y0 = (int)floorf(sy);
    x0 = min(max(x0, 0), W_ - 1);
    y0 = min(max(y0, 0), H_ - 1);
    const int x1 = min(x0 + 1, W_ - 1);
    const int y1 = min(y0 + 1, H_ - 1);
    const float wx1 = sx - (float)x0, wx0 = 1.0f - wx1;
    const float wy1 = sy - (float)y0, wy0 = 1.0f - wy1;

    const ushort4 g00 = *(const ushort4*)&vb[(size_t)(y0 * W_ + x0) * 256 + ch];
    const ushort4 g10 = *(const ushort4*)&vb[(size_t)(y0 * W_ + x1) * 256 + ch];
    const ushort4 g01 = *(const ushort4*)&vb[(size_t)(y1 * W_ + x0) * 256 + ch];
    const ushort4 g11 = *(const ushort4*)&vb[(size_t)(y1 * W_ + x1) * 256 + ch];

    const float w00 = wx0 * wy0, w10 = wx1 * wy0, w01 = wx0 * wy1, w11 = wx1 * wy1;
    const float wp = wt[p];
    const float f00[4] = {bf2f(g00.x), bf2f(g00.y), bf2f(g00.z), bf2f(g00.w)};
    const float f10[4] = {bf2f(g10.x), bf2f(g10.y), bf2f(g10.z), bf2f(g10.w)};
    const float f01[4] = {bf2f(g01.x), bf2f(g01.y), bf2f(g01.z), bf2f(g01.w)};
    const float f11[4] = {bf2f(g11.x), bf2f(g11.y), bf2f(g11.z), bf2f(g11.w)};
#pragma unroll
    for (int j = 0; j < 4; ++j)
      acc[j] += wp * (f00[j] * w00 + f01[j] * w01 + f10[j] * w10 + f11[j] * w11);
  }
  ushort4 mo;
  mo.x = f2bf_rn(acc[0]); mo.y = f2bf_rn(acc[1]);
  mo.z = f2bf_rn(acc[2]); mo.w = f2bf_rn(acc[3]);
  *(ushort4*)&mid[(size_t)bq * 256 + ch] = mo;
}

// ---------------------------------------------------------------------------
extern "C" void kernel_launch(void* const* d_in, const int* in_sizes, int n_in,
                              void* d_out, int out_size, void* d_ws, size_t ws_size,
                              hipStream_t stream)
{
  const float* query   = (const float*)d_in[0];
  const float* refp    = (const float*)d_in[1];
  const float* input_f = (const float*)d_in[2];
  const int*   hptr    = (const int*)d_in[3];
  const int*   wptr    = (const int*)d_in[4];
  const float* W_off   = (const float*)d_in[5];
  const float* b_off   = (const float*)d_in[6];
  const float* W_attn  = (const float*)d_in[7];
  const float* b_attn  = (const float*)d_in[8];
  const float* W_val   = (const float*)d_in[9];
  const float* b_val   = (const float*)d_in[10];
  const float* W_out   = (const float*)d_in[11];
  const float* b_out   = (const float*)d_in[12];
  float* out = (float*)d_out;

  const int D   = 256;
  const int BQ  = in_sizes[0] / D;   // 16384
  const int B   = 8;
  const int Q   = BQ / B;            // 2048
  const int BHW = in_sizes[2] / D;   // 80000
  const int HW  = BHW / B;           // 10000

  char* ws = (char*)d_ws;
  ushort* values = (ushort*)ws;                                 // bf16: 40.96 MB
  size_t o = (size_t)BHW * D * sizeof(ushort);
  float* pobuf  = (float*)(ws + o);  o += (size_t)BQ * 128 * sizeof(float);   // 8.39 MB
  ushort* midb  = (ushort*)(ws + o); o += (size_t)BQ * D * sizeof(ushort);    // 8.39 MB
  ushort* Bprep_val = (ushort*)(ws + o);  o += (size_t)8 * 8192 * sizeof(ushort);  // 128 KB
  ushort* Bprep_out = (ushort*)(ws + o);  o += (size_t)8 * 8192 * sizeof(ushort);  // 128 KB
  ushort* Bprep_po  = (ushort*)(ws + o);  o += (size_t)8 * 8192 * sizeof(ushort);  // 128 KB

  const int npo = BQ / 32;   // 512 proj blocks

  // 0. all weight preps in one launch
  prep_wt3<<<768, 256, 0, stream>>>(W_val, W_out, W_off, W_attn,
                                    Bprep_val, Bprep_out, Bprep_po);

  // 1+2 fused: proj (blocks 0..511) + gemm1 (blocks 512..1761)
  fused_g1_proj<<<npo + BHW / 64, 256, 0, stream>>>(
      input_f, Bprep_val, b_val, values,
      query, Bprep_po, b_off, b_attn, pobuf, npo);

  // 3. softmax + bilinear sampling -> mid (bf16), batch-per-XCD swizzled
  sample_kernel<<<BQ / 4, 256, 0, stream>>>(
      refp, pobuf, values, midb, hptr, wptr, Q, HW);

  // 4. out = mid @ W_out + b_out  (fp32 C, bf16 A)
  gemm2_kernel<<<BQ / 32, 256, 0, stream>>>(
      midb, Bprep_out, b_out, out);
}